// Round 16
// baseline (1591.712 us; speedup 1.0000x reference)
//
#include <hip/hip_runtime.h>

#define DT_C   0.1f
#define INV1P  0.9090909090909091f  /* 1/(1+DT) */

typedef short bf16x8 __attribute__((ext_vector_type(8)));
typedef float f32x4  __attribute__((ext_vector_type(4)));

// ---------------- bf16 pack (RNE) ----------------

__device__ __forceinline__ unsigned bf16rne(float f) {
  unsigned b = __float_as_uint(f);
  return (b + 0x7fffu + ((b >> 16) & 1u)) >> 16;
}
__device__ __forceinline__ unsigned packbf(float x, float y) {
  return bf16rne(x) | (bf16rne(y) << 16);
}

// ---------------- fp8 e4m3 pack/unpack (HW cvt on gfx950; sw fallback) ----------------

#if __has_builtin(__builtin_amdgcn_cvt_pk_fp8_f32) && __has_builtin(__builtin_amdgcn_cvt_pk_f32_fp8)
typedef float vf2 __attribute__((ext_vector_type(2)));
__device__ __forceinline__ unsigned pk4_fp8(float a, float b, float c, float d) {
  int v = __builtin_amdgcn_cvt_pk_fp8_f32(a, b, 0, false);
  v = __builtin_amdgcn_cvt_pk_fp8_f32(c, d, v, true);
  return (unsigned)v;
}
__device__ __forceinline__ void unpk4_fp8(unsigned v, float& a, float& b, float& c, float& d) {
  vf2 lo = __builtin_amdgcn_cvt_pk_f32_fp8((int)v, false);
  vf2 hi = __builtin_amdgcn_cvt_pk_f32_fp8((int)v, true);
  a = lo[0]; b = lo[1]; c = hi[0]; d = hi[1];
}
#else
__device__ __forceinline__ unsigned enc8(float f) {
  unsigned u = __float_as_uint(f);
  unsigned mag = u & 0x7fffffffu;
  if (mag > 0x43E00000u) mag = 0x43E00000u;
  unsigned r = mag + 0x7FFFFu + ((mag >> 20) & 1u);
  int e8 = (int)(r >> 23) - 120;
  unsigned code = 0;
  if (e8 > 0) code = ((unsigned)(e8 > 15 ? 15 : e8) << 3) | ((r >> 20) & 7u);
  return code | ((u >> 24) & 0x80u);
}
__device__ __forceinline__ float dec8(unsigned c) {
  unsigned e = (c >> 3) & 15u, m = c & 7u, s = (c & 0x80u) << 24;
  if (e == 0) return __uint_as_float(s);
  return __uint_as_float(s | ((e + 120u) << 23) | (m << 20));
}
__device__ __forceinline__ unsigned pk4_fp8(float a, float b, float c, float d) {
  return enc8(a) | (enc8(b) << 8) | (enc8(c) << 16) | (enc8(d) << 24);
}
__device__ __forceinline__ void unpk4_fp8(unsigned v, float& a, float& b, float& c, float& d) {
  a = dec8(v & 0xffu); b = dec8((v >> 8) & 0xffu);
  c = dec8((v >> 16) & 0xffu); d = dec8(v >> 24);
}
#endif

// ---------------- setup: degree / scan(+dinv) / CSR fill ----------------

__global__ __launch_bounds__(256) void k_deg(const int* __restrict__ dst,
                                             int* __restrict__ deg, int e) {
  int i = blockIdx.x * 256 + threadIdx.x;
  if (i < e) atomicAdd(&deg[dst[i]], 1);
}

__global__ __launch_bounds__(1024) void k_scanA(const int* __restrict__ deg,
                                                int* __restrict__ rowptr,
                                                int* __restrict__ bsum,
                                                float* __restrict__ dinv, int n) {
  __shared__ int sm[1024];
  int t = threadIdx.x;
  int i = blockIdx.x * 1024 + t;
  int v = (i < n) ? deg[i] : 0;
  if (i < n) dinv[i] = rsqrtf(fmaxf((float)v, 1.0f));
  sm[t] = v;
  __syncthreads();
  for (int off = 1; off < 1024; off <<= 1) {
    int u = (t >= off) ? sm[t - off] : 0;
    __syncthreads();
    sm[t] += u;
    __syncthreads();
  }
  if (i < n) rowptr[i] = sm[t] - v;
  if (t == 1023) bsum[blockIdx.x] = sm[t];
}

__global__ __launch_bounds__(1024) void k_scanB(int* __restrict__ bsum, int g) {
  __shared__ int sm[1024];
  int t = threadIdx.x;
  int v = (t < g) ? bsum[t] : 0;
  sm[t] = v;
  __syncthreads();
  for (int off = 1; off < 1024; off <<= 1) {
    int u = (t >= off) ? sm[t - off] : 0;
    __syncthreads();
    sm[t] += u;
    __syncthreads();
  }
  if (t < g) bsum[t] = sm[t] - v;
}

__global__ __launch_bounds__(1024) void k_scanC(int* __restrict__ rowptr,
                                                const int* __restrict__ bsum,
                                                int n, int etot) {
  int i = blockIdx.x * 1024 + threadIdx.x;
  if (i < n) rowptr[i] += bsum[blockIdx.x];
  if (i == 0) rowptr[n] = etot;
}

// packed CSR word: bits[16:0]=src (N<2^17), bits[31:17]=float bits of w (RNE)
// csr write via atomicExch: executes at L2, allocates the line there ->
// 16 edge-writes per 64B row accumulate in-cache, one writeback (vs 17x
// partial-line HBM writes for the plain store, measured WRITE_SIZE 108MB).
__global__ __launch_bounds__(256) void k_fill(const int* __restrict__ src,
                                              const int* __restrict__ dst,
                                              const int* __restrict__ rowptr,
                                              int* __restrict__ deg,
                                              const float* __restrict__ dinv,
                                              unsigned* __restrict__ csr, int e) {
  int i = blockIdx.x * 256 + threadIdx.x;
  if (i >= e) return;
  int s = src[i], d = dst[i];
  int pos = rowptr[d] + atomicSub(&deg[d], 1) - 1;
  unsigned wb = __float_as_uint(dinv[s] * dinv[d]);
  wb = (wb + 0x10000u) & 0xFFFE0000u;
  atomicExch(&csr[pos], wb | (unsigned)s);
}

// ---------------- input GEMM via MFMA (R15-proven) ----------------

#define WPAD 72   /* LDS row stride in dwords: 16B-aligned, not mult of 32 banks */

__global__ __launch_bounds__(256) void k_gemm_in(const float* __restrict__ x,
                                                 const float* __restrict__ Wlx,
                                                 const float* __restrict__ blx,
                                                 unsigned* __restrict__ h_b,
                                                 unsigned* __restrict__ rhs8,
                                                 int n, int ntiles) {
  __shared__ unsigned wt[64 * WPAD];
  __shared__ unsigned xb[16 * WPAD];
  int t = threadIdx.x;
  int lane = t & 63;
  int wib  = t >> 6;
  int ml = lane & 15;
  int kg = lane >> 4;
  int nb = wib * 16;
  int c  = nb + ml;

  for (int i = t; i < 4096; i += 256) {
    int nc = i & 63, kp = i >> 6;
    wt[nc * WPAD + kp] = packbf(Wlx[(2 * kp) * 64 + nc], Wlx[(2 * kp + 1) * 64 + nc]);
  }
  float bl = blx[c];
  __syncthreads();

  for (int tile = blockIdx.x; tile < ntiles; tile += gridDim.x) {
    int base = tile * 16;
    for (int i = t; i < 1024; i += 256) {
      int r = i >> 6, kp = i & 63;
      unsigned pw = 0;
      if (base + r < n) {
        float2 f = *(const float2*)(x + (size_t)(base + r) * 128 + 2 * kp);
        pw = packbf(f.x, f.y);
      }
      xb[r * WPAD + kp] = pw;
    }
    __syncthreads();

    f32x4 acc = {bl, bl, bl, bl};
#pragma unroll
    for (int kk = 0; kk < 4; ++kk) {
      bf16x8 a = *(const bf16x8*)&xb[ml * WPAD + kk * 16 + kg * 4];
      bf16x8 b = *(const bf16x8*)&wt[(nb + ml) * WPAD + kk * 16 + kg * 4];
      acc = __builtin_amdgcn_mfma_f32_16x16x32_bf16(a, b, acc, 0, 0, 0);
    }

    float tv[4], u1[4], u2[4], u3[4];
#pragma unroll
    for (int j = 0; j < 4; ++j) tv[j] = tanhf(acc[j]);
#pragma unroll
    for (int j = 0; j < 4; ++j) {
      u1[j] = __shfl_xor(tv[j], 1);
      u2[j] = __shfl_xor(tv[j], 2);
      u3[j] = __shfl_xor(u1[j], 2);
    }
    if ((ml & 1) == 0) {
#pragma unroll
      for (int j = 0; j < 4; ++j) {
        int row = base + kg * 4 + j;
        if (row < n) h_b[(size_t)row * 64 + (c >> 1)] = packbf(tv[j], u1[j]);
      }
    } else {
#pragma unroll
      for (int j = 0; j < 4; ++j) {
        int row = base + kg * 4 + j;
        if (row < n) h_b[(size_t)row * 64 + 32 + (c >> 1)] = 0x3f803f80u;
      }
    }
    if ((ml & 3) == 0) {
      int wq = c >> 2;
#pragma unroll
      for (int j = 0; j < 4; ++j) {
        int row = base + kg * 4 + j;
        if (row < n) {
          rhs8[(size_t)row * 32 + wq] = pk4_fp8(tv[j], u1[j], u2[j], u3[j]);
          rhs8[(size_t)row * 32 + 16 + wq] =
              pk4_fp8(1.f + DT_C * (tv[j] - 1.f), 1.f + DT_C * (u1[j] - 1.f),
                      1.f + DT_C * (u2[j] - 1.f), 1.f + DT_C * (u3[j] - 1.f));
        }
      }
    }
    __syncthreads();
  }
}

// ---------------- gather helper (R12-proven): 8-ch partial sums from fp8 matrix ----------------

__device__ __forceinline__ void gather8(const unsigned* __restrict__ Zb8,
                                        const unsigned* __restrict__ csr,
                                        int beg, int end, int g, int q,
                                        float acc[8]) {
#pragma unroll
  for (int i = 0; i < 8; ++i) acc[i] = 0.f;
  int last = end - 1;
  const uint2* Z2 = (const uint2*)Zb8;
  for (int e0 = beg; e0 < end; e0 += 16) {
    unsigned c[4]; float wk[4]; uint2 u[4];
#pragma unroll
    for (int k = 0; k < 4; ++k) {
      int idx = e0 + 4 * k + g;
      int ic  = (idx < end) ? idx : last;
      c[k]  = csr[ic];
      wk[k] = (idx < end) ? __uint_as_float(c[k] & 0xFFFE0000u) : 0.f;
    }
#pragma unroll
    for (int k = 0; k < 4; ++k)
      u[k] = Z2[(size_t)(c[k] & 0x1FFFFu) * 16 + q];
#pragma unroll
    for (int k = 0; k < 4; ++k) {
      float f0, f1, f2, f3, f4, f5, f6, f7;
      unpk4_fp8(u[k].x, f0, f1, f2, f3);
      unpk4_fp8(u[k].y, f4, f5, f6, f7);
      acc[0] = fmaf(wk[k], f0, acc[0]);
      acc[1] = fmaf(wk[k], f1, acc[1]);
      acc[2] = fmaf(wk[k], f2, acc[2]);
      acc[3] = fmaf(wk[k], f3, acc[3]);
      acc[4] = fmaf(wk[k], f4, acc[4]);
      acc[5] = fmaf(wk[k], f5, acc[5]);
      acc[6] = fmaf(wk[k], f6, acc[6]);
      acc[7] = fmaf(wk[k], f7, acc[7]);
    }
  }
#pragma unroll
  for (int i = 0; i < 8; ++i) {
    acc[i] += __shfl_xor(acc[i], 16);
    acc[i] += __shfl_xor(acc[i], 32);
  }
}

// ---------------- phase A: Z1 = (r + DT*agg(rhs8)) / (1+DT), r read from rhs8 ----------------

__global__ __launch_bounds__(256) void k_aggA(const unsigned* __restrict__ rhs8,
                                              unsigned* __restrict__ Z18,
                                              const int* __restrict__ rowptr,
                                              const unsigned* __restrict__ csr, int n) {
  int node = __builtin_amdgcn_readfirstlane((blockIdx.x * 256 + threadIdx.x) >> 6);
  if (node >= n) return;
  int lane = threadIdx.x & 63;
  int g = lane >> 4, q = lane & 15;
  int beg = __builtin_amdgcn_readfirstlane(rowptr[node]);
  int end = __builtin_amdgcn_readfirstlane(rowptr[node + 1]);

  uint2 rr = ((const uint2*)rhs8)[(size_t)node * 16 + q];

  float acc[8];
  gather8(rhs8, csr, beg, end, g, q, acc);

  float r8[8];
  unpk4_fp8(rr.x, r8[0], r8[1], r8[2], r8[3]);
  unpk4_fp8(rr.y, r8[4], r8[5], r8[6], r8[7]);
  if (g == 0) {
    uint2 o;
    o.x = pk4_fp8((r8[0] + DT_C * acc[0]) * INV1P, (r8[1] + DT_C * acc[1]) * INV1P,
                  (r8[2] + DT_C * acc[2]) * INV1P, (r8[3] + DT_C * acc[3]) * INV1P);
    o.y = pk4_fp8((r8[4] + DT_C * acc[4]) * INV1P, (r8[5] + DT_C * acc[5]) * INV1P,
                  (r8[6] + DT_C * acc[6]) * INV1P, (r8[7] + DT_C * acc[7]) * INV1P);
    ((uint2*)Z18)[(size_t)node * 16 + q] = o;
  }
}

// ---------------- phase B (R12-proven): Z2 -> h update -> new rhs8 ----------------

__device__ __forceinline__ void rch_from_h(const uint4 hb, int q,
                                           float hv[8], float rch[8]) {
  unsigned hw[4] = {hb.x, hb.y, hb.z, hb.w};
#pragma unroll
  for (int i = 0; i < 4; ++i) {
    hv[2 * i]     = __uint_as_float(hw[i] << 16);
    hv[2 * i + 1] = __uint_as_float(hw[i] & 0xffff0000u);
  }
  float pv[8];
#pragma unroll
  for (int i = 0; i < 8; ++i) pv[i] = __shfl_xor(hv[i], 8);
  bool isX = (q < 8);
#pragma unroll
  for (int i = 0; i < 8; ++i)
    rch[i] = isX ? hv[i] + DT_C * hv[i] * (1.0f - pv[i])
                 : hv[i] + DT_C * hv[i] * (pv[i] - 1.0f);
}

__global__ __launch_bounds__(256) void k_aggB(const unsigned* __restrict__ Z18,
                                              unsigned* __restrict__ rhs8,
                                              unsigned* __restrict__ h_b,
                                              const int* __restrict__ rowptr,
                                              const unsigned* __restrict__ csr,
                                              const float* __restrict__ taus,
                                              int layer, int n) {
  int node = __builtin_amdgcn_readfirstlane((blockIdx.x * 256 + threadIdx.x) >> 6);
  if (node >= n) return;
  int lane = threadIdx.x & 63;
  int g = lane >> 4, q = lane & 15;
  int beg = __builtin_amdgcn_readfirstlane(rowptr[node]);
  int end = __builtin_amdgcn_readfirstlane(rowptr[node + 1]);

  uint4 hb = *((const uint4*)(h_b + (size_t)node * 64) + q);
  float hv[8], rch[8];
  rch_from_h(hb, q, hv, rch);

  float acc[8];
  gather8(Z18, csr, beg, end, g, q, acc);

  float tv  = taus[layer];
  float tau = 1.0f / (1.0f + expf(-tv));
  float hnew[8];
#pragma unroll
  for (int i = 0; i < 8; ++i) {
    float z = (rch[i] + DT_C * acc[i]) * INV1P;
    hnew[i] = (1.0f - tau) * hv[i] + tau * z;
  }
  if (g == 0) {
    uint4 o;
    o.x = packbf(hnew[0], hnew[1]);
    o.y = packbf(hnew[2], hnew[3]);
    o.z = packbf(hnew[4], hnew[5]);
    o.w = packbf(hnew[6], hnew[7]);
    *((uint4*)(h_b + (size_t)node * 64) + q) = o;
  }
  float pn[8];
#pragma unroll
  for (int i = 0; i < 8; ++i) pn[i] = __shfl_xor(hnew[i], 8);
  bool isX = (q < 8);
  float rn[8];
#pragma unroll
  for (int i = 0; i < 8; ++i)
    rn[i] = isX ? hnew[i] + DT_C * hnew[i] * (1.0f - pn[i])
                : hnew[i] + DT_C * hnew[i] * (pn[i] - 1.0f);
  if (g == 0) {
    uint2 o;
    o.x = pk4_fp8(rn[0], rn[1], rn[2], rn[3]);
    o.y = pk4_fp8(rn[4], rn[5], rn[6], rn[7]);
    ((uint2*)rhs8)[(size_t)node * 16 + q] = o;
  }
}

// ---------------- readout GEMM (R12-proven) ----------------

__global__ __launch_bounds__(256) void k_gemm_out(const unsigned* __restrict__ h_b,
                                                  const float* __restrict__ Wro,
                                                  const float* __restrict__ bro,
                                                  const float* __restrict__ lscale,
                                                  float* __restrict__ out, int n) {
  __shared__ float ws[64 * 40];
  __shared__ float xs[16 * 64];
  int t = threadIdx.x;
  for (int i = t; i < 64 * 40; i += 256) ws[i] = Wro[i];
  int base = blockIdx.x * 16;
  for (int v = t; v < 512; v += 256) {
    int rr = v >> 5;
    int wq = v & 31;
    int row = base + rr;
    float a = 0.f, b = 0.f;
    if (row < n) {
      unsigned u = h_b[(size_t)row * 64 + wq];
      a = __uint_as_float(u << 16);
      b = __uint_as_float(u & 0xffff0000u);
    }
    xs[rr * 64 + 2 * wq]     = a;
    xs[rr * 64 + 2 * wq + 1] = b;
  }
  __syncthreads();
  float ls = *lscale;
  int lane = t & 63;
  int wib  = t >> 6;
  float bb = (lane < 40) ? bro[lane] : 0.f;
  for (int r = 0; r < 4; ++r) {
    int row = base + wib * 4 + r;
    if (row < n && lane < 40) {
      const float* xr = &xs[(wib * 4 + r) * 64];
      float acc = 0.f;
#pragma unroll
      for (int k = 0; k < 64; ++k) acc = fmaf(xr[k], ws[k * 40 + lane], acc);
      out[row * 40 + lane] = ls * acc + bb;
    }
  }
}

// ---------------- launch ----------------

extern "C" void kernel_launch(void* const* d_in, const int* in_sizes, int n_in,
                              void* d_out, int out_size, void* d_ws, size_t ws_size,
                              hipStream_t stream) {
  const float* x     = (const float*)d_in[0];
  const float* Wlx   = (const float*)d_in[1];
  const float* blx   = (const float*)d_in[2];
  const float* taus  = (const float*)d_in[5];
  const float* lsc   = (const float*)d_in[6];
  const float* Wro   = (const float*)d_in[7];
  const float* bro   = (const float*)d_in[8];
  const int*   eidx  = (const int*)d_in[9];
  int n = in_sizes[0] / 128;
  int e = in_sizes[9] / 2;
  const int* srcp = eidx;
  const int* dstp = eidx + e;
  float* out = (float*)d_out;

  char* ws = (char*)d_ws;
  size_t off = 0;
  auto alloc = [&](size_t bytes) -> void* {
    void* p = ws + off;
    off += (bytes + 255) & ~(size_t)255;
    return p;
  };
  int*      deg     = (int*)     alloc((size_t)n * 4);
  float*    dinv    = (float*)   alloc((size_t)n * 4);
  int*      rowptr  = (int*)     alloc((size_t)(n + 1) * 4);
  int*      bsum    = (int*)     alloc(1024 * 4);
  unsigned* csr     = (unsigned*)alloc((size_t)e * 4);
  unsigned* h_b     = (unsigned*)alloc((size_t)n * 64 * 4);
  unsigned* rhs8    = (unsigned*)alloc((size_t)n * 32 * 4);
  unsigned* Z18     = (unsigned*)alloc((size_t)n * 32 * 4);
  (void)ws_size; (void)n_in; (void)out_size;

  (void)hipMemsetAsync(deg, 0, (size_t)n * 4, stream);

  int eb = (e + 255) / 256;
  int sb = (n + 1023) / 1024;
  k_deg <<<eb, 256, 0, stream>>>(dstp, deg, e);
  k_scanA<<<sb, 1024, 0, stream>>>(deg, rowptr, bsum, dinv, n);
  k_scanB<<<1, 1024, 0, stream>>>(bsum, sb);
  k_scanC<<<sb, 1024, 0, stream>>>(rowptr, bsum, n, e);
  k_fill<<<eb, 256, 0, stream>>>(srcp, dstp, rowptr, deg, dinv, csr, e);

  int ntiles = (n + 15) / 16;
  int gb = ntiles < 1024 ? ntiles : 1024;
  k_gemm_in<<<gb, 256, 0, stream>>>(x, Wlx, blx, h_b, rhs8, n, ntiles);

  int ab = (n * 64 + 255) / 256;  // one wave per node
  for (int l = 0; l < 15; ++l) {
    k_aggA<<<ab, 256, 0, stream>>>(rhs8, Z18, rowptr, csr, n);
    k_aggB<<<ab, 256, 0, stream>>>(Z18, rhs8, h_b, rowptr, csr, taus, l, n);
  }

  k_gemm_out<<<(n + 15) / 16, 256, 0, stream>>>(h_b, Wro, bro, lsc, out, n);
}

// Round 17
// 1535.351 us; speedup vs baseline: 1.0367x; 1.0367x over previous
//
#include <hip/hip_runtime.h>

#define DT_C   0.1f
#define INV1P  0.9090909090909091f  /* 1/(1+DT) */

typedef short bf16x8 __attribute__((ext_vector_type(8)));
typedef float f32x4  __attribute__((ext_vector_type(4)));

// ---------------- bf16 pack (RNE) ----------------

__device__ __forceinline__ unsigned bf16rne(float f) {
  unsigned b = __float_as_uint(f);
  return (b + 0x7fffu + ((b >> 16) & 1u)) >> 16;
}
__device__ __forceinline__ unsigned packbf(float x, float y) {
  return bf16rne(x) | (bf16rne(y) << 16);
}

// ---------------- fp8 e4m3 pack/unpack (HW cvt on gfx950; sw fallback) ----------------

#if __has_builtin(__builtin_amdgcn_cvt_pk_fp8_f32) && __has_builtin(__builtin_amdgcn_cvt_pk_f32_fp8)
typedef float vf2 __attribute__((ext_vector_type(2)));
__device__ __forceinline__ unsigned pk4_fp8(float a, float b, float c, float d) {
  int v = __builtin_amdgcn_cvt_pk_fp8_f32(a, b, 0, false);
  v = __builtin_amdgcn_cvt_pk_fp8_f32(c, d, v, true);
  return (unsigned)v;
}
__device__ __forceinline__ void unpk4_fp8(unsigned v, float& a, float& b, float& c, float& d) {
  vf2 lo = __builtin_amdgcn_cvt_pk_f32_fp8((int)v, false);
  vf2 hi = __builtin_amdgcn_cvt_pk_f32_fp8((int)v, true);
  a = lo[0]; b = lo[1]; c = hi[0]; d = hi[1];
}
#else
__device__ __forceinline__ unsigned enc8(float f) {
  unsigned u = __float_as_uint(f);
  unsigned mag = u & 0x7fffffffu;
  if (mag > 0x43E00000u) mag = 0x43E00000u;
  unsigned r = mag + 0x7FFFFu + ((mag >> 20) & 1u);
  int e8 = (int)(r >> 23) - 120;
  unsigned code = 0;
  if (e8 > 0) code = ((unsigned)(e8 > 15 ? 15 : e8) << 3) | ((r >> 20) & 7u);
  return code | ((u >> 24) & 0x80u);
}
__device__ __forceinline__ float dec8(unsigned c) {
  unsigned e = (c >> 3) & 15u, m = c & 7u, s = (c & 0x80u) << 24;
  if (e == 0) return __uint_as_float(s);
  return __uint_as_float(s | ((e + 120u) << 23) | (m << 20));
}
__device__ __forceinline__ unsigned pk4_fp8(float a, float b, float c, float d) {
  return enc8(a) | (enc8(b) << 8) | (enc8(c) << 16) | (enc8(d) << 24);
}
__device__ __forceinline__ void unpk4_fp8(unsigned v, float& a, float& b, float& c, float& d) {
  a = dec8(v & 0xffu); b = dec8((v >> 8) & 0xffu);
  c = dec8((v >> 16) & 0xffu); d = dec8(v >> 24);
}
#endif

// ---------------- setup: degree / scan(+dinv) / CSR fill ----------------

__global__ __launch_bounds__(256) void k_deg(const int* __restrict__ dst,
                                             int* __restrict__ deg, int e) {
  int i = blockIdx.x * 256 + threadIdx.x;
  if (i < e) atomicAdd(&deg[dst[i]], 1);
}

__global__ __launch_bounds__(1024) void k_scanA(const int* __restrict__ deg,
                                                int* __restrict__ rowptr,
                                                int* __restrict__ bsum,
                                                float* __restrict__ dinv, int n) {
  __shared__ int sm[1024];
  int t = threadIdx.x;
  int i = blockIdx.x * 1024 + t;
  int v = (i < n) ? deg[i] : 0;
  if (i < n) dinv[i] = rsqrtf(fmaxf((float)v, 1.0f));
  sm[t] = v;
  __syncthreads();
  for (int off = 1; off < 1024; off <<= 1) {
    int u = (t >= off) ? sm[t - off] : 0;
    __syncthreads();
    sm[t] += u;
    __syncthreads();
  }
  if (i < n) rowptr[i] = sm[t] - v;
  if (t == 1023) bsum[blockIdx.x] = sm[t];
}

__global__ __launch_bounds__(1024) void k_scanB(int* __restrict__ bsum, int g) {
  __shared__ int sm[1024];
  int t = threadIdx.x;
  int v = (t < g) ? bsum[t] : 0;
  sm[t] = v;
  __syncthreads();
  for (int off = 1; off < 1024; off <<= 1) {
    int u = (t >= off) ? sm[t - off] : 0;
    __syncthreads();
    sm[t] += u;
    __syncthreads();
  }
  if (t < g) bsum[t] = sm[t] - v;
}

__global__ __launch_bounds__(1024) void k_scanC(int* __restrict__ rowptr,
                                                const int* __restrict__ bsum,
                                                int n, int etot) {
  int i = blockIdx.x * 1024 + threadIdx.x;
  if (i < n) rowptr[i] += bsum[blockIdx.x];
  if (i == 0) rowptr[n] = etot;
}

// packed CSR word: bits[16:0]=src (N<2^17), bits[31:17]=float bits of w (RNE)
// Plain store: 17x write amplification is structural (cross-XCD 4B scatter;
// atomicExch variant measured SLOWER at 127us, R16; dst-sort variant +150us, R9).
__global__ __launch_bounds__(256) void k_fill(const int* __restrict__ src,
                                              const int* __restrict__ dst,
                                              const int* __restrict__ rowptr,
                                              int* __restrict__ deg,
                                              const float* __restrict__ dinv,
                                              unsigned* __restrict__ csr, int e) {
  int i = blockIdx.x * 256 + threadIdx.x;
  if (i >= e) return;
  int s = src[i], d = dst[i];
  int pos = rowptr[d] + atomicSub(&deg[d], 1) - 1;
  unsigned wb = __float_as_uint(dinv[s] * dinv[d]);
  wb = (wb + 0x10000u) & 0xFFFE0000u;
  csr[pos] = wb | (unsigned)s;
}

// ---------------- input GEMM via MFMA (R15-proven) ----------------

#define WPAD 72   /* LDS row stride in dwords: 16B-aligned, not mult of 32 banks */

__global__ __launch_bounds__(256) void k_gemm_in(const float* __restrict__ x,
                                                 const float* __restrict__ Wlx,
                                                 const float* __restrict__ blx,
                                                 unsigned* __restrict__ h_b,
                                                 unsigned* __restrict__ rhs8,
                                                 int n, int ntiles) {
  __shared__ unsigned wt[64 * WPAD];
  __shared__ unsigned xb[16 * WPAD];
  int t = threadIdx.x;
  int lane = t & 63;
  int wib  = t >> 6;
  int ml = lane & 15;
  int kg = lane >> 4;
  int nb = wib * 16;
  int c  = nb + ml;

  for (int i = t; i < 4096; i += 256) {
    int nc = i & 63, kp = i >> 6;
    wt[nc * WPAD + kp] = packbf(Wlx[(2 * kp) * 64 + nc], Wlx[(2 * kp + 1) * 64 + nc]);
  }
  float bl = blx[c];
  __syncthreads();

  for (int tile = blockIdx.x; tile < ntiles; tile += gridDim.x) {
    int base = tile * 16;
    for (int i = t; i < 1024; i += 256) {
      int r = i >> 6, kp = i & 63;
      unsigned pw = 0;
      if (base + r < n) {
        float2 f = *(const float2*)(x + (size_t)(base + r) * 128 + 2 * kp);
        pw = packbf(f.x, f.y);
      }
      xb[r * WPAD + kp] = pw;
    }
    __syncthreads();

    f32x4 acc = {bl, bl, bl, bl};
#pragma unroll
    for (int kk = 0; kk < 4; ++kk) {
      bf16x8 a = *(const bf16x8*)&xb[ml * WPAD + kk * 16 + kg * 4];
      bf16x8 b = *(const bf16x8*)&wt[(nb + ml) * WPAD + kk * 16 + kg * 4];
      acc = __builtin_amdgcn_mfma_f32_16x16x32_bf16(a, b, acc, 0, 0, 0);
    }

    float tv[4], u1[4], u2[4], u3[4];
#pragma unroll
    for (int j = 0; j < 4; ++j) tv[j] = tanhf(acc[j]);
#pragma unroll
    for (int j = 0; j < 4; ++j) {
      u1[j] = __shfl_xor(tv[j], 1);
      u2[j] = __shfl_xor(tv[j], 2);
      u3[j] = __shfl_xor(u1[j], 2);
    }
    if ((ml & 1) == 0) {
#pragma unroll
      for (int j = 0; j < 4; ++j) {
        int row = base + kg * 4 + j;
        if (row < n) h_b[(size_t)row * 64 + (c >> 1)] = packbf(tv[j], u1[j]);
      }
    } else {
#pragma unroll
      for (int j = 0; j < 4; ++j) {
        int row = base + kg * 4 + j;
        if (row < n) h_b[(size_t)row * 64 + 32 + (c >> 1)] = 0x3f803f80u;
      }
    }
    if ((ml & 3) == 0) {
      int wq = c >> 2;
#pragma unroll
      for (int j = 0; j < 4; ++j) {
        int row = base + kg * 4 + j;
        if (row < n) {
          rhs8[(size_t)row * 32 + wq] = pk4_fp8(tv[j], u1[j], u2[j], u3[j]);
          rhs8[(size_t)row * 32 + 16 + wq] =
              pk4_fp8(1.f + DT_C * (tv[j] - 1.f), 1.f + DT_C * (u1[j] - 1.f),
                      1.f + DT_C * (u2[j] - 1.f), 1.f + DT_C * (u3[j] - 1.f));
        }
      }
    }
    __syncthreads();
  }
}

// ---------------- gather helper (R12-proven): 8-ch partial sums from fp8 matrix ----------------

__device__ __forceinline__ void gather8(const unsigned* __restrict__ Zb8,
                                        const unsigned* __restrict__ csr,
                                        int beg, int end, int g, int q,
                                        float acc[8]) {
#pragma unroll
  for (int i = 0; i < 8; ++i) acc[i] = 0.f;
  int last = end - 1;
  const uint2* Z2 = (const uint2*)Zb8;
  for (int e0 = beg; e0 < end; e0 += 16) {
    unsigned c[4]; float wk[4]; uint2 u[4];
#pragma unroll
    for (int k = 0; k < 4; ++k) {
      int idx = e0 + 4 * k + g;
      int ic  = (idx < end) ? idx : last;
      c[k]  = csr[ic];
      wk[k] = (idx < end) ? __uint_as_float(c[k] & 0xFFFE0000u) : 0.f;
    }
#pragma unroll
    for (int k = 0; k < 4; ++k)
      u[k] = Z2[(size_t)(c[k] & 0x1FFFFu) * 16 + q];
#pragma unroll
    for (int k = 0; k < 4; ++k) {
      float f0, f1, f2, f3, f4, f5, f6, f7;
      unpk4_fp8(u[k].x, f0, f1, f2, f3);
      unpk4_fp8(u[k].y, f4, f5, f6, f7);
      acc[0] = fmaf(wk[k], f0, acc[0]);
      acc[1] = fmaf(wk[k], f1, acc[1]);
      acc[2] = fmaf(wk[k], f2, acc[2]);
      acc[3] = fmaf(wk[k], f3, acc[3]);
      acc[4] = fmaf(wk[k], f4, acc[4]);
      acc[5] = fmaf(wk[k], f5, acc[5]);
      acc[6] = fmaf(wk[k], f6, acc[6]);
      acc[7] = fmaf(wk[k], f7, acc[7]);
    }
  }
#pragma unroll
  for (int i = 0; i < 8; ++i) {
    acc[i] += __shfl_xor(acc[i], 16);
    acc[i] += __shfl_xor(acc[i], 32);
  }
}

// ---------------- phase A: Z1 = (r + DT*agg(rhs8)) / (1+DT), r read from rhs8 ----------------

__global__ __launch_bounds__(256) void k_aggA(const unsigned* __restrict__ rhs8,
                                              unsigned* __restrict__ Z18,
                                              const int* __restrict__ rowptr,
                                              const unsigned* __restrict__ csr, int n) {
  int node = __builtin_amdgcn_readfirstlane((blockIdx.x * 256 + threadIdx.x) >> 6);
  if (node >= n) return;
  int lane = threadIdx.x & 63;
  int g = lane >> 4, q = lane & 15;
  int beg = __builtin_amdgcn_readfirstlane(rowptr[node]);
  int end = __builtin_amdgcn_readfirstlane(rowptr[node + 1]);

  uint2 rr = ((const uint2*)rhs8)[(size_t)node * 16 + q];

  float acc[8];
  gather8(rhs8, csr, beg, end, g, q, acc);

  float r8[8];
  unpk4_fp8(rr.x, r8[0], r8[1], r8[2], r8[3]);
  unpk4_fp8(rr.y, r8[4], r8[5], r8[6], r8[7]);
  if (g == 0) {
    uint2 o;
    o.x = pk4_fp8((r8[0] + DT_C * acc[0]) * INV1P, (r8[1] + DT_C * acc[1]) * INV1P,
                  (r8[2] + DT_C * acc[2]) * INV1P, (r8[3] + DT_C * acc[3]) * INV1P);
    o.y = pk4_fp8((r8[4] + DT_C * acc[4]) * INV1P, (r8[5] + DT_C * acc[5]) * INV1P,
                  (r8[6] + DT_C * acc[6]) * INV1P, (r8[7] + DT_C * acc[7]) * INV1P);
    ((uint2*)Z18)[(size_t)node * 16 + q] = o;
  }
}

// ---------------- phase B (R12-proven): Z2 -> h update -> new rhs8 ----------------

__device__ __forceinline__ void rch_from_h(const uint4 hb, int q,
                                           float hv[8], float rch[8]) {
  unsigned hw[4] = {hb.x, hb.y, hb.z, hb.w};
#pragma unroll
  for (int i = 0; i < 4; ++i) {
    hv[2 * i]     = __uint_as_float(hw[i] << 16);
    hv[2 * i + 1] = __uint_as_float(hw[i] & 0xffff0000u);
  }
  float pv[8];
#pragma unroll
  for (int i = 0; i < 8; ++i) pv[i] = __shfl_xor(hv[i], 8);
  bool isX = (q < 8);
#pragma unroll
  for (int i = 0; i < 8; ++i)
    rch[i] = isX ? hv[i] + DT_C * hv[i] * (1.0f - pv[i])
                 : hv[i] + DT_C * hv[i] * (pv[i] - 1.0f);
}

__global__ __launch_bounds__(256) void k_aggB(const unsigned* __restrict__ Z18,
                                              unsigned* __restrict__ rhs8,
                                              unsigned* __restrict__ h_b,
                                              const int* __restrict__ rowptr,
                                              const unsigned* __restrict__ csr,
                                              const float* __restrict__ taus,
                                              int layer, int n) {
  int node = __builtin_amdgcn_readfirstlane((blockIdx.x * 256 + threadIdx.x) >> 6);
  if (node >= n) return;
  int lane = threadIdx.x & 63;
  int g = lane >> 4, q = lane & 15;
  int beg = __builtin_amdgcn_readfirstlane(rowptr[node]);
  int end = __builtin_amdgcn_readfirstlane(rowptr[node + 1]);

  uint4 hb = *((const uint4*)(h_b + (size_t)node * 64) + q);
  float hv[8], rch[8];
  rch_from_h(hb, q, hv, rch);

  float acc[8];
  gather8(Z18, csr, beg, end, g, q, acc);

  float tv  = taus[layer];
  float tau = 1.0f / (1.0f + expf(-tv));
  float hnew[8];
#pragma unroll
  for (int i = 0; i < 8; ++i) {
    float z = (rch[i] + DT_C * acc[i]) * INV1P;
    hnew[i] = (1.0f - tau) * hv[i] + tau * z;
  }
  if (g == 0) {
    uint4 o;
    o.x = packbf(hnew[0], hnew[1]);
    o.y = packbf(hnew[2], hnew[3]);
    o.z = packbf(hnew[4], hnew[5]);
    o.w = packbf(hnew[6], hnew[7]);
    *((uint4*)(h_b + (size_t)node * 64) + q) = o;
  }
  float pn[8];
#pragma unroll
  for (int i = 0; i < 8; ++i) pn[i] = __shfl_xor(hnew[i], 8);
  bool isX = (q < 8);
  float rn[8];
#pragma unroll
  for (int i = 0; i < 8; ++i)
    rn[i] = isX ? hnew[i] + DT_C * hnew[i] * (1.0f - pn[i])
                : hnew[i] + DT_C * hnew[i] * (pn[i] - 1.0f);
  if (g == 0) {
    uint2 o;
    o.x = pk4_fp8(rn[0], rn[1], rn[2], rn[3]);
    o.y = pk4_fp8(rn[4], rn[5], rn[6], rn[7]);
    ((uint2*)rhs8)[(size_t)node * 16 + q] = o;
  }
}

// ---------------- readout GEMM (R12-proven) ----------------

__global__ __launch_bounds__(256) void k_gemm_out(const unsigned* __restrict__ h_b,
                                                  const float* __restrict__ Wro,
                                                  const float* __restrict__ bro,
                                                  const float* __restrict__ lscale,
                                                  float* __restrict__ out, int n) {
  __shared__ float ws[64 * 40];
  __shared__ float xs[16 * 64];
  int t = threadIdx.x;
  for (int i = t; i < 64 * 40; i += 256) ws[i] = Wro[i];
  int base = blockIdx.x * 16;
  for (int v = t; v < 512; v += 256) {
    int rr = v >> 5;
    int wq = v & 31;
    int row = base + rr;
    float a = 0.f, b = 0.f;
    if (row < n) {
      unsigned u = h_b[(size_t)row * 64 + wq];
      a = __uint_as_float(u << 16);
      b = __uint_as_float(u & 0xffff0000u);
    }
    xs[rr * 64 + 2 * wq]     = a;
    xs[rr * 64 + 2 * wq + 1] = b;
  }
  __syncthreads();
  float ls = *lscale;
  int lane = t & 63;
  int wib  = t >> 6;
  float bb = (lane < 40) ? bro[lane] : 0.f;
  for (int r = 0; r < 4; ++r) {
    int row = base + wib * 4 + r;
    if (row < n && lane < 40) {
      const float* xr = &xs[(wib * 4 + r) * 64];
      float acc = 0.f;
#pragma unroll
      for (int k = 0; k < 64; ++k) acc = fmaf(xr[k], ws[k * 40 + lane], acc);
      out[row * 40 + lane] = ls * acc + bb;
    }
  }
}

// ---------------- launch ----------------

extern "C" void kernel_launch(void* const* d_in, const int* in_sizes, int n_in,
                              void* d_out, int out_size, void* d_ws, size_t ws_size,
                              hipStream_t stream) {
  const float* x     = (const float*)d_in[0];
  const float* Wlx   = (const float*)d_in[1];
  const float* blx   = (const float*)d_in[2];
  const float* taus  = (const float*)d_in[5];
  const float* lsc   = (const float*)d_in[6];
  const float* Wro   = (const float*)d_in[7];
  const float* bro   = (const float*)d_in[8];
  const int*   eidx  = (const int*)d_in[9];
  int n = in_sizes[0] / 128;
  int e = in_sizes[9] / 2;
  const int* srcp = eidx;
  const int* dstp = eidx + e;
  float* out = (float*)d_out;

  char* ws = (char*)d_ws;
  size_t off = 0;
  auto alloc = [&](size_t bytes) -> void* {
    void* p = ws + off;
    off += (bytes + 255) & ~(size_t)255;
    return p;
  };
  int*      deg     = (int*)     alloc((size_t)n * 4);
  float*    dinv    = (float*)   alloc((size_t)n * 4);
  int*      rowptr  = (int*)     alloc((size_t)(n + 1) * 4);
  int*      bsum    = (int*)     alloc(1024 * 4);
  unsigned* csr     = (unsigned*)alloc((size_t)e * 4);
  unsigned* h_b     = (unsigned*)alloc((size_t)n * 64 * 4);
  unsigned* rhs8    = (unsigned*)alloc((size_t)n * 32 * 4);
  unsigned* Z18     = (unsigned*)alloc((size_t)n * 32 * 4);
  (void)ws_size; (void)n_in; (void)out_size;

  (void)hipMemsetAsync(deg, 0, (size_t)n * 4, stream);

  int eb = (e + 255) / 256;
  int sb = (n + 1023) / 1024;
  k_deg <<<eb, 256, 0, stream>>>(dstp, deg, e);
  k_scanA<<<sb, 1024, 0, stream>>>(deg, rowptr, bsum, dinv, n);
  k_scanB<<<1, 1024, 0, stream>>>(bsum, sb);
  k_scanC<<<sb, 1024, 0, stream>>>(rowptr, bsum, n, e);
  k_fill<<<eb, 256, 0, stream>>>(srcp, dstp, rowptr, deg, dinv, csr, e);

  int ntiles = (n + 15) / 16;
  int gb = ntiles < 1024 ? ntiles : 1024;
  k_gemm_in<<<gb, 256, 0, stream>>>(x, Wlx, blx, h_b, rhs8, n, ntiles);

  int ab = (n * 64 + 255) / 256;  // one wave per node
  for (int l = 0; l < 15; ++l) {
    k_aggA<<<ab, 256, 0, stream>>>(rhs8, Z18, rowptr, csr, n);
    k_aggB<<<ab, 256, 0, stream>>>(Z18, rhs8, h_b, rowptr, csr, taus, l, n);
  }

  k_gemm_out<<<(n + 15) / 16, 256, 0, stream>>>(h_b, Wro, bro, lsc, out, n);
}